// Round 3
// baseline (453.965 us; speedup 1.0000x reference)
//
#include <hip/hip_runtime.h>

typedef unsigned short u16;
typedef unsigned int   u32;

__device__ __forceinline__ float b2f(u16 u){
  u32 x = ((u32)u) << 16;
  float f;
  __builtin_memcpy(&f, &x, 4);
  return f;
}
// dtype-flexible scalar element load: element index i, f32 flag
__device__ __forceinline__ float ld(const void* p, int i, bool f32){
  return f32 ? ((const float*)p)[i] : b2f(((const u16*)p)[i]);
}

// ---------------------------------------------------------------------------
// Kernel 0: input dtype detector. Decodes first 64 u16 of each tensor as
// bf16; a wave-max |value| over 1e6 is only possible if the storage is f32
// (f32 low-half u16s decode to random-exponent bf16s; true bf16 data here is
// bounded by ~6). Scalars: bf16(0.25)=0x3E80 != 0; low half of f32(0.25) is
// 0x0000 -> b2f==0 means f32.
// flags[0]=X, [1]=L, [2]=w, [3]=aw, [4]=scalars   (1.0 = f32, 0.0 = bf16)
// ---------------------------------------------------------------------------
__global__ __launch_bounds__(256) void k_detect(
    const u16* __restrict__ X, const u16* __restrict__ L,
    const u16* __restrict__ w, const u16* __restrict__ aw,
    const u16* __restrict__ pa, float* __restrict__ flags)
{
  const int tid  = threadIdx.x;
  const int g    = tid >> 6;        // 0..3 -> X, L, w, aw
  const int lane = tid & 63;
  const u16* src = (g == 0) ? X : (g == 1) ? L : (g == 2) ? w : aw;
  float v = fabsf(b2f(src[lane]));
  if (!(v < 1e30f)) v = 1e30f;      // inf/nan -> huge
#pragma unroll
  for (int off = 32; off; off >>= 1){
    float o = __shfl_xor(v, off);
    v = v > o ? v : o;
  }
  if (lane == 0) flags[g] = (v > 1e6f) ? 1.f : 0.f;
  if (tid == 0)  flags[4] = (b2f(pa[0]) == 0.f) ? 1.f : 0.f;
}

// ---------------------------------------------------------------------------
// Kernel A: src/dst projections. One wave per (b,n) row; lane = channel c.
// Also zero-inits denom[8192] (blocks 0..31).
// ---------------------------------------------------------------------------
__global__ __launch_bounds__(256) void k_srcdst(
    const void* __restrict__ Xr, const void* __restrict__ Xi,
    const void* __restrict__ awr, const void* __restrict__ awi,
    float* __restrict__ src_r, float* __restrict__ src_i,
    float* __restrict__ dst_r, float* __restrict__ dst_i,
    float* __restrict__ denom, const float* __restrict__ flags)
{
  const int tid = threadIdx.x;
  if (blockIdx.x < 32) denom[blockIdx.x * 256 + tid] = 0.f;

  const bool fX  = flags[0] != 0.f;
  const bool fAW = flags[3] != 0.f;

  const int bn = blockIdx.x * 4 + (tid >> 6);
  const int c  = tid & 63;
  float xr = ld(Xr, bn * 64 + c, fX);
  float xi = ld(Xi, bn * 64 + c, fX);
  float wsr = ld(awr, c, fAW),      wsi = ld(awi, c, fAW);
  float wdr = ld(awr, 64 + c, fAW), wdi = ld(awi, 64 + c, fAW);

  float p0 = xr * wsr - xi * wsi;   // src_r
  float p1 = xr * wsi + xi * wsr;   // src_i
  float p2 = xr * wdr - xi * wdi;   // dst_r
  float p3 = xr * wdi + xi * wdr;   // dst_i
#pragma unroll
  for (int off = 32; off; off >>= 1){
    p0 += __shfl_xor(p0, off);
    p1 += __shfl_xor(p1, off);
    p2 += __shfl_xor(p2, off);
    p3 += __shfl_xor(p3, off);
  }
  if (c == 0){
    src_r[bn] = p0; src_i[bn] = p1; dst_r[bn] = p2; dst_i[bn] = p3;
  }
}

// ---------------------------------------------------------------------------
// Kernel B: column softmax denominators. softmax is over axis=1 (source index
// n) for each (b, m). mag in [0, ~30] -> exp safe without max-subtraction.
// grid = 8 b * 4 m-chunks * 8 n-chunks; partials merged with atomicAdd.
// ---------------------------------------------------------------------------
__global__ __launch_bounds__(256) void k_colsum(
    const float* __restrict__ src_r, const float* __restrict__ src_i,
    const float* __restrict__ dst_r, const float* __restrict__ dst_i,
    const void* __restrict__ abr_p, const void* __restrict__ abi_p,
    const void* __restrict__ par_p, const void* __restrict__ pai_p,
    float* __restrict__ denom, const float* __restrict__ flags)
{
  __shared__ float srs[128], sis[128];
  const int tid = threadIdx.x;
  const int b  = blockIdx.x >> 5;
  const int mc = (blockIdx.x >> 3) & 3;
  const int nc = blockIdx.x & 7;
  const int m  = mc * 256 + tid;

  const bool fS = flags[4] != 0.f;
  const float abr = ld(abr_p, 0, fS), abi = ld(abi_p, 0, fS);
  const float par = ld(par_p, 0, fS), pai = ld(pai_p, 0, fS);

  if (tid < 128) srs[tid] = src_r[b * 1024 + nc * 128 + tid];
  else           sis[tid - 128] = src_i[b * 1024 + nc * 128 + (tid - 128)];
  __syncthreads();

  const float dr = dst_r[b * 1024 + m];
  const float di = dst_i[b * 1024 + m];
  float sum = 0.f;
#pragma unroll 4
  for (int j = 0; j < 128; j++){
    float sr = srs[j] + dr + abr; sr = sr >= 0.f ? sr : par * sr;
    float si = sis[j] + di + abi; si = si >= 0.f ? si : pai * si;
    float mag = sqrtf(sr * sr + si * si);
    sum += __expf(mag);
  }
  atomicAdd(&denom[b * 1024 + m], sum);
}

// ---------------------------------------------------------------------------
// Kernel C: the HBM-bound kernel. One block per (b,n); thread t owns
// m in [4t, 4t+4). Streams L_real/L_imag (16B coalesced in either dtype),
// computes attention coefficients once (reused across 5 k), accumulates
// SLr[k] = sum_m (Lr*a_r - Li*a_i), SLi[k] = sum_m (Lr*a_i + Li*a_r),
// block-reduces, writes SL[bn][10] = [SLr0..4, SLi0..4].
// ---------------------------------------------------------------------------
__global__ __launch_bounds__(256) void k_rowsum(
    const void* __restrict__ Lr, const void* __restrict__ Li,
    const float* __restrict__ src_r, const float* __restrict__ src_i,
    const float* __restrict__ dst_r, const float* __restrict__ dst_i,
    const float* __restrict__ denom,
    const void* __restrict__ abr_p, const void* __restrict__ abi_p,
    const void* __restrict__ par_p, const void* __restrict__ pai_p,
    float* __restrict__ SL, const float* __restrict__ flags)
{
  const int tid = threadIdx.x;
  const int bn  = blockIdx.x;
  const int b   = bn >> 10;
  const int n   = bn & 1023;

  const bool fL = flags[1] != 0.f;
  const bool fS = flags[4] != 0.f;

  // Issue the long-latency HBM loads first: 5 k * {real, imag} 16B vectors.
  // Vector index math is identical in float4 or ushort4 units (256/row).
  const int base = b * 5 * 262144 + n * 256 + tid;
  float lr[5][4], li[5][4];
  if (fL){
    const float4* LrP = (const float4*)Lr;
    const float4* LiP = (const float4*)Li;
#pragma unroll
    for (int k = 0; k < 5; k++){
      float4 a = LrP[base + k * 262144];
      float4 c = LiP[base + k * 262144];
      lr[k][0]=a.x; lr[k][1]=a.y; lr[k][2]=a.z; lr[k][3]=a.w;
      li[k][0]=c.x; li[k][1]=c.y; li[k][2]=c.z; li[k][3]=c.w;
    }
  } else {
    const ushort4* LrP = (const ushort4*)Lr;
    const ushort4* LiP = (const ushort4*)Li;
#pragma unroll
    for (int k = 0; k < 5; k++){
      ushort4 a = LrP[base + k * 262144];
      ushort4 c = LiP[base + k * 262144];
      lr[k][0]=b2f(a.x); lr[k][1]=b2f(a.y); lr[k][2]=b2f(a.z); lr[k][3]=b2f(a.w);
      li[k][0]=b2f(c.x); li[k][1]=b2f(c.y); li[k][2]=b2f(c.z); li[k][3]=b2f(c.w);
    }
  }

  const int mb = b * 1024 + tid * 4;
  float4 dr4 = *(const float4*)(dst_r + mb);
  float4 di4 = *(const float4*)(dst_i + mb);
  float4 de4 = *(const float4*)(denom + mb);
  const float sR = src_r[bn], sI = src_i[bn];
  const float abr = ld(abr_p, 0, fS), abi = ld(abi_p, 0, fS);
  const float par = ld(par_p, 0, fS), pai = ld(pai_p, 0, fS);

  float drv[4], dvv[4], dev[4];
  *(float4*)drv = dr4; *(float4*)dvv = di4; *(float4*)dev = de4;

  float ar[4], ai[4];
#pragma unroll
  for (int j = 0; j < 4; j++){
    float sr = sR + drv[j] + abr; sr = sr >= 0.f ? sr : par * sr;
    float si = sI + dvv[j] + abi; si = si >= 0.f ? si : pai * si;
    float mag = sqrtf(sr * sr + si * si);
    float e = __expf(mag);
    float safe = mag > 0.f ? mag : 1.f;
    float coef = e / (dev[j] * safe);   // sm / safe
    ar[j] = coef * sr;
    ai[j] = coef * si;
  }

  float v[10];
#pragma unroll
  for (int k = 0; k < 5; k++){
    float accr = 0.f, acci = 0.f;
#pragma unroll
    for (int j = 0; j < 4; j++){
      accr += lr[k][j] * ar[j] - li[k][j] * ai[j];
      acci += lr[k][j] * ai[j] + li[k][j] * ar[j];
    }
    v[k]     = accr;
    v[5 + k] = acci;
  }

#pragma unroll
  for (int off = 32; off; off >>= 1){
#pragma unroll
    for (int t = 0; t < 10; t++) v[t] += __shfl_xor(v[t], off);
  }
  __shared__ float red[4][10];
  if ((tid & 63) == 0){
#pragma unroll
    for (int t = 0; t < 10; t++) red[tid >> 6][t] = v[t];
  }
  __syncthreads();
  if (tid < 10)
    SL[bn * 10 + tid] = red[0][tid] + red[1][tid] + red[2][tid] + red[3][tid];
}

// ---------------------------------------------------------------------------
// Kernel D: out[b,n,o] from SL and X@w. Block = 16 rows; thread = (r, 4 o's).
// Shares Dr = Xr@wr[k], Di = Xi@wi[k] between out_r and out_i.
// w staged per-k into LDS transposed, +4 pad (stride 68).
// OUTPUT IS FLOAT32 (reference output dtype) — staged via LDS, float4 stores.
// ---------------------------------------------------------------------------
__global__ __launch_bounds__(256) void k_out(
    const void* __restrict__ Xr, const void* __restrict__ Xi,
    const void* __restrict__ wr, const void* __restrict__ wi,
    const float* __restrict__ SL, float* __restrict__ out,
    const float* __restrict__ flags)
{
  __shared__ __align__(16) float Xr_s[16 * 68];
  __shared__ __align__(16) float Xi_s[16 * 68];
  __shared__ __align__(16) float wrT[64 * 68];
  __shared__ __align__(16) float wiT[64 * 68];
  __shared__ float SL_s[160];

  const int tid = threadIdx.x;
  const int R0  = blockIdx.x * 16;
  const bool fX = flags[0] != 0.f;
  const bool fW = flags[2] != 0.f;

#pragma unroll
  for (int e = 0; e < 4; e++){
    int idx = tid + 256 * e;              // [0,1024)
    int r = idx >> 6, c = idx & 63;
    Xr_s[r * 68 + c] = ld(Xr, R0 * 64 + idx, fX);
    Xi_s[r * 68 + c] = ld(Xi, R0 * 64 + idx, fX);
  }
  if (tid < 160) SL_s[tid] = SL[R0 * 10 + tid];

  const int r  = tid & 15;
  const int o4 = tid >> 4;
  float outr[4] = {0.f, 0.f, 0.f, 0.f};
  float outi[4] = {0.f, 0.f, 0.f, 0.f};

  for (int k = 0; k < 5; k++){
    __syncthreads();   // also covers initial X/SL staging at k=0
#pragma unroll
    for (int e = 0; e < 16; e++){
      int idx = tid + 256 * e;            // [0,4096)
      int c = idx >> 6, o = idx & 63;     // w[k][c][o], o contiguous in global
      wrT[o * 68 + c] = ld(wr, k * 4096 + idx, fW);
      wiT[o * 68 + c] = ld(wi, k * 4096 + idx, fW);
    }
    __syncthreads();

    float Dr[4] = {0.f, 0.f, 0.f, 0.f};
    float Di[4] = {0.f, 0.f, 0.f, 0.f};
#pragma unroll 4
    for (int c0 = 0; c0 < 64; c0 += 4){
      float4 xr = *(const float4*)(Xr_s + r * 68 + c0);
      float4 xi = *(const float4*)(Xi_s + r * 68 + c0);
#pragma unroll
      for (int oo = 0; oo < 4; oo++){
        int o = o4 * 4 + oo;
        float4 a  = *(const float4*)(wrT + o * 68 + c0);
        float4 bb = *(const float4*)(wiT + o * 68 + c0);
        Dr[oo] += xr.x * a.x  + xr.y * a.y  + xr.z * a.z  + xr.w * a.w;
        Di[oo] += xi.x * bb.x + xi.y * bb.y + xi.z * bb.z + xi.w * bb.w;
      }
    }
    const float slr = SL_s[r * 10 + k];
    const float sli = SL_s[r * 10 + 5 + k];
#pragma unroll
    for (int oo = 0; oo < 4; oo++){
      outr[oo] += slr * Dr[oo] - sli * Di[oo];
      outi[oo] += sli * Dr[oo] + slr * Di[oo];
    }
  }

  // Stage outputs through LDS (reuse wrT/wiT) for coalesced f32 stores.
  __syncthreads();
#pragma unroll
  for (int oo = 0; oo < 4; oo++){
    int o = o4 * 4 + oo;
    wrT[r * 68 + o] = outr[oo];
    wiT[r * 68 + o] = outi[oo];
  }
  __syncthreads();
  {
    int flat = tid * 4;                   // [0,1024) = 16 rows * 64 o
    int rr = flat >> 6, o0 = flat & 63;
    float4 vr = *(const float4*)(wrT + rr * 68 + o0);
    float4 vi = *(const float4*)(wiT + rr * 68 + o0);
    *(float4*)(out + (R0 + rr) * 64 + o0)          = vr;   // out_r
    *(float4*)(out + 524288 + (R0 + rr) * 64 + o0) = vi;   // out_i
  }
}

// ---------------------------------------------------------------------------
// Launch. Workspace layout (floats):
//   [0)      src_r[8192]
//   [8192)   src_i[8192]
//   [16384)  dst_r[8192]
//   [24576)  dst_i[8192]
//   [32768)  denom[8192]
//   [40960)  SL[8192*10]
//   [122880) flags[5]
// Total ~480 KB.
// ---------------------------------------------------------------------------
extern "C" void kernel_launch(void* const* d_in, const int* in_sizes, int n_in,
                              void* d_out, int out_size, void* d_ws, size_t ws_size,
                              hipStream_t stream)
{
  const void* Xr  = d_in[0];
  const void* Xi  = d_in[1];
  const void* Lr  = d_in[2];
  const void* Li  = d_in[3];
  const void* wrp = d_in[4];
  const void* wip = d_in[5];
  const void* awr = d_in[6];
  const void* awi = d_in[7];
  const void* abr = d_in[8];
  const void* abi = d_in[9];
  const void* par = d_in[10];
  const void* pai = d_in[11];
  float* out = (float*)d_out;

  float* ws    = (float*)d_ws;
  float* src_r = ws;
  float* src_i = ws + 8192;
  float* dst_r = ws + 16384;
  float* dst_i = ws + 24576;
  float* denom = ws + 32768;
  float* SL    = ws + 40960;
  float* flags = ws + 122880;

  k_detect<<<1, 256, 0, stream>>>((const u16*)Xr, (const u16*)Lr, (const u16*)wrp,
                                  (const u16*)awr, (const u16*)par, flags);
  k_srcdst<<<2048, 256, 0, stream>>>(Xr, Xi, awr, awi, src_r, src_i, dst_r, dst_i,
                                     denom, flags);
  k_colsum<<<256, 256, 0, stream>>>(src_r, src_i, dst_r, dst_i, abr, abi, par, pai,
                                    denom, flags);
  k_rowsum<<<8192, 256, 0, stream>>>(Lr, Li, src_r, src_i, dst_r, dst_i, denom,
                                     abr, abi, par, pai, SL, flags);
  k_out<<<512, 256, 0, stream>>>(Xr, Xi, wrp, wip, SL, out, flags);
}

// Round 4
// 424.664 us; speedup vs baseline: 1.0690x; 1.0690x over previous
//
#include <hip/hip_runtime.h>

typedef unsigned short u16;
typedef unsigned int   u32;

__device__ __forceinline__ float b2f(u16 u){
  u32 x = ((u32)u) << 16;
  float f;
  __builtin_memcpy(&f, &x, 4);
  return f;
}
// dtype-flexible scalar element load: element index i, f32 flag
__device__ __forceinline__ float ld(const void* p, int i, bool f32){
  return f32 ? ((const float*)p)[i] : b2f(((const u16*)p)[i]);
}

// ---------------------------------------------------------------------------
// Kernel 0: input dtype detector. Decodes first 64 u16 of each tensor as
// bf16; wave-max |value| > 1e6 is only possible if storage is f32. Scalars:
// bf16(0.25)=0x3E80 != 0; low half of f32(0.25)=0x0000 -> b2f==0 means f32.
// flags[0]=X, [1]=L, [2]=w, [3]=aw, [4]=scalars   (1.0 = f32, 0.0 = bf16)
// ---------------------------------------------------------------------------
__global__ __launch_bounds__(256) void k_detect(
    const u16* __restrict__ X, const u16* __restrict__ L,
    const u16* __restrict__ w, const u16* __restrict__ aw,
    const u16* __restrict__ pa, float* __restrict__ flags)
{
  const int tid  = threadIdx.x;
  const int g    = tid >> 6;        // 0..3 -> X, L, w, aw
  const int lane = tid & 63;
  const u16* src = (g == 0) ? X : (g == 1) ? L : (g == 2) ? w : aw;
  float v = fabsf(b2f(src[lane]));
  if (!(v < 1e30f)) v = 1e30f;      // inf/nan -> huge
#pragma unroll
  for (int off = 32; off; off >>= 1){
    float o = __shfl_xor(v, off);
    v = v > o ? v : o;
  }
  if (lane == 0) flags[g] = (v > 1e6f) ? 1.f : 0.f;
  if (tid == 0)  flags[4] = (b2f(pa[0]) == 0.f) ? 1.f : 0.f;
}

// ---------------------------------------------------------------------------
// Kernel A: src/dst projections. One wave per (b,n) row; lane = channel c.
// Also zero-inits denom[8192] (blocks 0..31).
// ---------------------------------------------------------------------------
__global__ __launch_bounds__(256) void k_srcdst(
    const void* __restrict__ Xr, const void* __restrict__ Xi,
    const void* __restrict__ awr, const void* __restrict__ awi,
    float* __restrict__ src_r, float* __restrict__ src_i,
    float* __restrict__ dst_r, float* __restrict__ dst_i,
    float* __restrict__ denom, const float* __restrict__ flags)
{
  const int tid = threadIdx.x;
  if (blockIdx.x < 32) denom[blockIdx.x * 256 + tid] = 0.f;

  const bool fX  = flags[0] != 0.f;
  const bool fAW = flags[3] != 0.f;

  const int bn = blockIdx.x * 4 + (tid >> 6);
  const int c  = tid & 63;
  float xr = ld(Xr, bn * 64 + c, fX);
  float xi = ld(Xi, bn * 64 + c, fX);
  float wsr = ld(awr, c, fAW),      wsi = ld(awi, c, fAW);
  float wdr = ld(awr, 64 + c, fAW), wdi = ld(awi, 64 + c, fAW);

  float p0 = xr * wsr - xi * wsi;   // src_r
  float p1 = xr * wsi + xi * wsr;   // src_i
  float p2 = xr * wdr - xi * wdi;   // dst_r
  float p3 = xr * wdi + xi * wdr;   // dst_i
#pragma unroll
  for (int off = 32; off; off >>= 1){
    p0 += __shfl_xor(p0, off);
    p1 += __shfl_xor(p1, off);
    p2 += __shfl_xor(p2, off);
    p3 += __shfl_xor(p3, off);
  }
  if (c == 0){
    src_r[bn] = p0; src_i[bn] = p1; dst_r[bn] = p2; dst_i[bn] = p3;
  }
}

// ---------------------------------------------------------------------------
// Kernel B: column softmax denominators (softmax over axis=1).
// mag in [0, ~30] -> exp safe without max-subtraction.
// ---------------------------------------------------------------------------
__global__ __launch_bounds__(256) void k_colsum(
    const float* __restrict__ src_r, const float* __restrict__ src_i,
    const float* __restrict__ dst_r, const float* __restrict__ dst_i,
    const void* __restrict__ abr_p, const void* __restrict__ abi_p,
    const void* __restrict__ par_p, const void* __restrict__ pai_p,
    float* __restrict__ denom, const float* __restrict__ flags)
{
  __shared__ float srs[128], sis[128];
  const int tid = threadIdx.x;
  const int b  = blockIdx.x >> 5;
  const int mc = (blockIdx.x >> 3) & 3;
  const int nc = blockIdx.x & 7;
  const int m  = mc * 256 + tid;

  const bool fS = flags[4] != 0.f;
  const float abr = ld(abr_p, 0, fS), abi = ld(abi_p, 0, fS);
  const float par = ld(par_p, 0, fS), pai = ld(pai_p, 0, fS);

  if (tid < 128) srs[tid] = src_r[b * 1024 + nc * 128 + tid];
  else           sis[tid - 128] = src_i[b * 1024 + nc * 128 + (tid - 128)];
  __syncthreads();

  const float dr = dst_r[b * 1024 + m];
  const float di = dst_i[b * 1024 + m];
  float sum = 0.f;
#pragma unroll 4
  for (int j = 0; j < 128; j++){
    float sr = srs[j] + dr + abr; sr = sr >= 0.f ? sr : par * sr;
    float si = sis[j] + di + abi; si = si >= 0.f ? si : pai * si;
    float mag = sqrtf(sr * sr + si * si);
    sum += __expf(mag);
  }
  atomicAdd(&denom[b * 1024 + m], sum);
}

// ---------------------------------------------------------------------------
// Kernel C v2: ONE WAVE PER (b,n) ROW. No barriers, no cross-wave LDS.
// Lane owns 4 consecutive m per j-chunk (j=0..3 covers m=0..1023).
// Manual 1-deep double-buffer prefetch keeps ~13 loads in flight per wave.
// One 10-value butterfly reduce per row at the end. v_rcp/v_sqrt approx math
// (threshold headroom is ~80x).
// ---------------------------------------------------------------------------
__global__ __launch_bounds__(256, 4) void k_rowsum(
    const void* __restrict__ Lr, const void* __restrict__ Li,
    const float* __restrict__ src_r, const float* __restrict__ src_i,
    const float* __restrict__ dst_r, const float* __restrict__ dst_i,
    const float* __restrict__ denom,
    const void* __restrict__ abr_p, const void* __restrict__ abi_p,
    const void* __restrict__ par_p, const void* __restrict__ pai_p,
    float* __restrict__ SL, const float* __restrict__ flags)
{
  const int tid  = threadIdx.x;
  const int lane = tid & 63;
  const int bn   = blockIdx.x * 4 + (tid >> 6);   // 2048 blocks * 4 waves
  const int b    = bn >> 10;
  const int n    = bn & 1023;

  const bool fL = flags[1] != 0.f;
  const bool fS = flags[4] != 0.f;

  const float sR = src_r[bn], sI = src_i[bn];
  const float abr = ld(abr_p, 0, fS), abi = ld(abi_p, 0, fS);
  const float par = ld(par_p, 0, fS), pai = ld(pai_p, 0, fS);

  float acc[10];
#pragma unroll
  for (int t = 0; t < 10; t++) acc[t] = 0.f;

  const int rowbase = (b * 5 * 1024 + n) * 256;   // in 4-element-vector units
  const int dbase   = b * 1024;

  if (!fL){
    // ---- bf16 L fast path ----
    const ushort4* LrP = (const ushort4*)Lr;
    const ushort4* LiP = (const ushort4*)Li;
    ushort4 lb[2][5], mb[2][5];
    float4 dr4[2], di4[2], de4[2];
#pragma unroll
    for (int k = 0; k < 5; k++){
      lb[0][k] = LrP[rowbase + k * 262144 + lane];
      mb[0][k] = LiP[rowbase + k * 262144 + lane];
    }
    dr4[0] = *(const float4*)(dst_r + dbase + lane * 4);
    di4[0] = *(const float4*)(dst_i + dbase + lane * 4);
    de4[0] = *(const float4*)(denom + dbase + lane * 4);

#pragma unroll
    for (int j = 0; j < 4; j++){
      const int cur = j & 1, nxt = cur ^ 1;
      if (j < 3){
        const int voff = (j + 1) * 64 + lane;
#pragma unroll
        for (int k = 0; k < 5; k++){
          lb[nxt][k] = LrP[rowbase + k * 262144 + voff];
          mb[nxt][k] = LiP[rowbase + k * 262144 + voff];
        }
        dr4[nxt] = *(const float4*)(dst_r + dbase + voff * 4);
        di4[nxt] = *(const float4*)(dst_i + dbase + voff * 4);
        de4[nxt] = *(const float4*)(denom + dbase + voff * 4);
      }
      float drv[4] = {dr4[cur].x, dr4[cur].y, dr4[cur].z, dr4[cur].w};
      float dvv[4] = {di4[cur].x, di4[cur].y, di4[cur].z, di4[cur].w};
      float dev[4] = {de4[cur].x, de4[cur].y, de4[cur].z, de4[cur].w};
      float ar[4], ai[4];
#pragma unroll
      for (int q = 0; q < 4; q++){
        float sr = sR + drv[q] + abr; sr = sr >= 0.f ? sr : par * sr;
        float si = sI + dvv[q] + abi; si = si >= 0.f ? si : pai * si;
        float mag = __builtin_amdgcn_sqrtf(sr * sr + si * si);
        float e = __expf(mag);
        float safe = mag > 0.f ? mag : 1.f;
        float coef = e * __builtin_amdgcn_rcpf(dev[q] * safe);
        ar[q] = coef * sr;
        ai[q] = coef * si;
      }
#pragma unroll
      for (int k = 0; k < 5; k++){
        float l0 = b2f(lb[cur][k].x), l1 = b2f(lb[cur][k].y);
        float l2 = b2f(lb[cur][k].z), l3 = b2f(lb[cur][k].w);
        float m0 = b2f(mb[cur][k].x), m1 = b2f(mb[cur][k].y);
        float m2 = b2f(mb[cur][k].z), m3 = b2f(mb[cur][k].w);
        float accr = acc[k], acci = acc[5 + k];
        accr += l0 * ar[0] - m0 * ai[0];
        accr += l1 * ar[1] - m1 * ai[1];
        accr += l2 * ar[2] - m2 * ai[2];
        accr += l3 * ar[3] - m3 * ai[3];
        acci += l0 * ai[0] + m0 * ar[0];
        acci += l1 * ai[1] + m1 * ar[1];
        acci += l2 * ai[2] + m2 * ar[2];
        acci += l3 * ai[3] + m3 * ar[3];
        acc[k] = accr; acc[5 + k] = acci;
      }
    }
  } else {
    // ---- f32 L path (correctness; not perf-critical) ----
    const float4* LrP = (const float4*)Lr;
    const float4* LiP = (const float4*)Li;
    for (int j = 0; j < 4; j++){
      const int voff = j * 64 + lane;
      float4 dr4 = *(const float4*)(dst_r + dbase + voff * 4);
      float4 di4 = *(const float4*)(dst_i + dbase + voff * 4);
      float4 de4 = *(const float4*)(denom + dbase + voff * 4);
      float drv[4] = {dr4.x, dr4.y, dr4.z, dr4.w};
      float dvv[4] = {di4.x, di4.y, di4.z, di4.w};
      float dev[4] = {de4.x, de4.y, de4.z, de4.w};
      float ar[4], ai[4];
#pragma unroll
      for (int q = 0; q < 4; q++){
        float sr = sR + drv[q] + abr; sr = sr >= 0.f ? sr : par * sr;
        float si = sI + dvv[q] + abi; si = si >= 0.f ? si : pai * si;
        float mag = __builtin_amdgcn_sqrtf(sr * sr + si * si);
        float e = __expf(mag);
        float safe = mag > 0.f ? mag : 1.f;
        float coef = e * __builtin_amdgcn_rcpf(dev[q] * safe);
        ar[q] = coef * sr;
        ai[q] = coef * si;
      }
#pragma unroll 1
      for (int k = 0; k < 5; k++){
        float4 a = LrP[rowbase + k * 262144 + voff];
        float4 c = LiP[rowbase + k * 262144 + voff];
        acc[k]     += a.x*ar[0] - c.x*ai[0] + a.y*ar[1] - c.y*ai[1]
                    + a.z*ar[2] - c.z*ai[2] + a.w*ar[3] - c.w*ai[3];
        acc[5 + k] += a.x*ai[0] + c.x*ar[0] + a.y*ai[1] + c.y*ar[1]
                    + a.z*ai[2] + c.z*ar[2] + a.w*ai[3] + c.w*ar[3];
      }
    }
  }

  // single per-row butterfly reduce (wave-local, no barriers)
#pragma unroll
  for (int off = 32; off; off >>= 1){
#pragma unroll
    for (int t = 0; t < 10; t++) acc[t] += __shfl_xor(acc[t], off);
  }
  if (lane == 0){
#pragma unroll
    for (int t = 0; t < 10; t++) SL[bn * 10 + t] = acc[t];
  }
}

// ---------------------------------------------------------------------------
// Kernel D: out[b,n,o] from SL and X@w. Block = 16 rows; thread = (r, 4 o's).
// Staging loads now vectorized (ushort4/float4). Output f32, LDS-staged.
// ---------------------------------------------------------------------------
__global__ __launch_bounds__(256) void k_out(
    const void* __restrict__ Xr, const void* __restrict__ Xi,
    const void* __restrict__ wr, const void* __restrict__ wi,
    const float* __restrict__ SL, float* __restrict__ out,
    const float* __restrict__ flags)
{
  __shared__ __align__(16) float Xr_s[16 * 68];
  __shared__ __align__(16) float Xi_s[16 * 68];
  __shared__ __align__(16) float wrT[64 * 68];
  __shared__ __align__(16) float wiT[64 * 68];
  __shared__ float SL_s[160];

  const int tid = threadIdx.x;
  const int R0  = blockIdx.x * 16;
  const bool fX = flags[0] != 0.f;
  const bool fW = flags[2] != 0.f;

  // X staging: 1024 elements as 256 x 4-vectors; rows are 16B-aligned
  // (68 floats = 272 B = 17*16) so float4 LDS writes are legal.
  {
    int base = tid * 4;
    int r = base >> 6, c = base & 63;
    if (!fX){
      ushort4 a = ((const ushort4*)Xr)[R0 * 16 + tid];
      ushort4 bb = ((const ushort4*)Xi)[R0 * 16 + tid];
      *(float4*)(Xr_s + r * 68 + c) = make_float4(b2f(a.x), b2f(a.y), b2f(a.z), b2f(a.w));
      *(float4*)(Xi_s + r * 68 + c) = make_float4(b2f(bb.x), b2f(bb.y), b2f(bb.z), b2f(bb.w));
    } else {
      *(float4*)(Xr_s + r * 68 + c) = ((const float4*)Xr)[R0 * 16 + tid];
      *(float4*)(Xi_s + r * 68 + c) = ((const float4*)Xi)[R0 * 16 + tid];
    }
  }
  if (tid < 160) SL_s[tid] = SL[R0 * 10 + tid];

  const int r  = tid & 15;
  const int o4 = tid >> 4;
  float outr[4] = {0.f, 0.f, 0.f, 0.f};
  float outi[4] = {0.f, 0.f, 0.f, 0.f};

  for (int k = 0; k < 5; k++){
    __syncthreads();   // also covers initial X/SL staging at k=0
    // w staging: 4096 elements as 4-vectors (4 consecutive o, same c).
#pragma unroll
    for (int e = 0; e < 4; e++){
      int vidx = tid + 256 * e;             // vector index within k-slab
      int base = vidx * 4;
      int c = base >> 6, o = base & 63;
      float w0r, w1r, w2r, w3r, w0i, w1i, w2i, w3i;
      if (!fW){
        ushort4 a = ((const ushort4*)wr)[k * 1024 + vidx];
        ushort4 bb = ((const ushort4*)wi)[k * 1024 + vidx];
        w0r = b2f(a.x); w1r = b2f(a.y); w2r = b2f(a.z); w3r = b2f(a.w);
        w0i = b2f(bb.x); w1i = b2f(bb.y); w2i = b2f(bb.z); w3i = b2f(bb.w);
      } else {
        float4 a = ((const float4*)wr)[k * 1024 + vidx];
        float4 bb = ((const float4*)wi)[k * 1024 + vidx];
        w0r = a.x; w1r = a.y; w2r = a.z; w3r = a.w;
        w0i = bb.x; w1i = bb.y; w2i = bb.z; w3i = bb.w;
      }
      wrT[(o + 0) * 68 + c] = w0r; wrT[(o + 1) * 68 + c] = w1r;
      wrT[(o + 2) * 68 + c] = w2r; wrT[(o + 3) * 68 + c] = w3r;
      wiT[(o + 0) * 68 + c] = w0i; wiT[(o + 1) * 68 + c] = w1i;
      wiT[(o + 2) * 68 + c] = w2i; wiT[(o + 3) * 68 + c] = w3i;
    }
    __syncthreads();

    float Dr[4] = {0.f, 0.f, 0.f, 0.f};
    float Di[4] = {0.f, 0.f, 0.f, 0.f};
#pragma unroll 4
    for (int c0 = 0; c0 < 64; c0 += 4){
      float4 xr = *(const float4*)(Xr_s + r * 68 + c0);
      float4 xi = *(const float4*)(Xi_s + r * 68 + c0);
#pragma unroll
      for (int oo = 0; oo < 4; oo++){
        int o = o4 * 4 + oo;
        float4 a  = *(const float4*)(wrT + o * 68 + c0);
        float4 bb = *(const float4*)(wiT + o * 68 + c0);
        Dr[oo] += xr.x * a.x  + xr.y * a.y  + xr.z * a.z  + xr.w * a.w;
        Di[oo] += xi.x * bb.x + xi.y * bb.y + xi.z * bb.z + xi.w * bb.w;
      }
    }
    const float slr = SL_s[r * 10 + k];
    const float sli = SL_s[r * 10 + 5 + k];
#pragma unroll
    for (int oo = 0; oo < 4; oo++){
      outr[oo] += slr * Dr[oo] - sli * Di[oo];
      outi[oo] += sli * Dr[oo] + slr * Di[oo];
    }
  }

  // Stage outputs through LDS (reuse wrT/wiT) for coalesced f32 stores.
  __syncthreads();
#pragma unroll
  for (int oo = 0; oo < 4; oo++){
    int o = o4 * 4 + oo;
    wrT[r * 68 + o] = outr[oo];
    wiT[r * 68 + o] = outi[oo];
  }
  __syncthreads();
  {
    int flat = tid * 4;                   // [0,1024) = 16 rows * 64 o
    int rr = flat >> 6, o0 = flat & 63;
    float4 vr = *(const float4*)(wrT + rr * 68 + o0);
    float4 vi = *(const float4*)(wiT + rr * 68 + o0);
    *(float4*)(out + (R0 + rr) * 64 + o0)          = vr;   // out_r
    *(float4*)(out + 524288 + (R0 + rr) * 64 + o0) = vi;   // out_i
  }
}

// ---------------------------------------------------------------------------
// Launch. Workspace layout (floats):
//   [0)      src_r[8192]   [8192) src_i   [16384) dst_r   [24576) dst_i
//   [32768)  denom[8192]   [40960) SL[8192*10]   [122880) flags[5]
// ---------------------------------------------------------------------------
extern "C" void kernel_launch(void* const* d_in, const int* in_sizes, int n_in,
                              void* d_out, int out_size, void* d_ws, size_t ws_size,
                              hipStream_t stream)
{
  const void* Xr  = d_in[0];
  const void* Xi  = d_in[1];
  const void* Lr  = d_in[2];
  const void* Li  = d_in[3];
  const void* wrp = d_in[4];
  const void* wip = d_in[5];
  const void* awr = d_in[6];
  const void* awi = d_in[7];
  const void* abr = d_in[8];
  const void* abi = d_in[9];
  const void* par = d_in[10];
  const void* pai = d_in[11];
  float* out = (float*)d_out;

  float* ws    = (float*)d_ws;
  float* src_r = ws;
  float* src_i = ws + 8192;
  float* dst_r = ws + 16384;
  float* dst_i = ws + 24576;
  float* denom = ws + 32768;
  float* SL    = ws + 40960;
  float* flags = ws + 122880;

  k_detect<<<1, 256, 0, stream>>>((const u16*)Xr, (const u16*)Lr, (const u16*)wrp,
                                  (const u16*)awr, (const u16*)par, flags);
  k_srcdst<<<2048, 256, 0, stream>>>(Xr, Xi, awr, awi, src_r, src_i, dst_r, dst_i,
                                     denom, flags);
  k_colsum<<<256, 256, 0, stream>>>(src_r, src_i, dst_r, dst_i, abr, abi, par, pai,
                                    denom, flags);
  k_rowsum<<<2048, 256, 0, stream>>>(Lr, Li, src_r, src_i, dst_r, dst_i, denom,
                                     abr, abi, par, pai, SL, flags);
  k_out<<<512, 256, 0, stream>>>(Xr, Xi, wrp, wip, SL, out, flags);
}